// Round 4
// baseline (63.569 us; speedup 1.0000x reference)
//
#include <hip/hip_runtime.h>

#define EPS 1e-5f

typedef float fvec4 __attribute__((ext_vector_type(4)));

__device__ __forceinline__ float frelu(float x) { return x > 0.f ? x : 0.f; }
__device__ __forceinline__ float fast_rcp(float x) { return __builtin_amdgcn_rcpf(x); }
__device__ __forceinline__ float fast_rsq(float x) { return __builtin_amdgcn_rsqf(x); }

// Block = 512 threads, 2 rows/thread (1024 rows/block; B = 4096 * 1024 exactly).
//  - history: one aligned float4 per lane (2 rows x 2 f32), fully coalesced.
//  - paper/author: staged via LDS with coalesced float4 global loads
//    (1280 float4 per array per block); per-thread LDS reads lds[10t+j]
//    (4-way bank conflict, negligible: ~20 reads/thread at 1.58x).
//  - out: 3 aligned nontemporal f32x4 per lane (2 rows x 6 f32 = 48 B) so the
//    streamed output doesn't evict the L3-resident inputs across replays.
__global__ __launch_bounds__(512) void shattn_main(
    const float* __restrict__ history,
    const float* __restrict__ paper,
    const float* __restrict__ author,
    const float* __restrict__ g_W_h, const float* __restrict__ g_b_h,
    const float* __restrict__ g_W_p, const float* __restrict__ g_b_p,
    const float* __restrict__ g_W_a, const float* __restrict__ g_b_a,
    const float* __restrict__ g_ln_w, const float* __restrict__ g_ln_b,
    const float* __restrict__ g_W_fc, const float* __restrict__ g_b_fc,
    float* __restrict__ out)
{
    __shared__ float sp[84];
    __shared__ float pap[5120];   // 1024 rows x 5 f32 = 20 KB
    __shared__ float aut[5120];   // 20 KB

    const int t = threadIdx.x;
    const size_t rowbase = (size_t)blockIdx.x * 1024;

    // ---- independent global loads first (max ILP before the barrier) ----
    const float4 hq = reinterpret_cast<const float4*>(history)[rowbase / 2 + t];

    const float4* p4 = reinterpret_cast<const float4*>(paper  + rowbase * 5);
    const float4* a4 = reinterpret_cast<const float4*>(author + rowbase * 5);
    float4* pl = reinterpret_cast<float4*>(pap);
    float4* al = reinterpret_cast<float4*>(aut);
    const float4 pv0 = p4[t],        av0 = a4[t];
    const float4 pv1 = p4[512 + t],  av1 = a4[512 + t];
    float4 pv2, av2;
    if (t < 256) { pv2 = p4[1024 + t]; av2 = a4[1024 + t]; }

    if (t < 84) {
        float v;
        if      (t < 4)  v = g_W_h[t];
        else if (t < 6)  v = g_b_h[t - 4];
        else if (t < 16) v = g_W_p[t - 6];
        else if (t < 18) v = g_b_p[t - 16];
        else if (t < 28) v = g_W_a[t - 18];
        else if (t < 30) v = g_b_a[t - 28];
        else if (t < 36) v = g_ln_w[t - 30];
        else if (t < 42) v = g_ln_b[t - 36];
        else if (t < 78) v = g_W_fc[t - 42];
        else             v = g_b_fc[t - 78];
        sp[t] = v;
    }

    pl[t] = pv0;        al[t] = av0;
    pl[512 + t] = pv1;  al[512 + t] = av1;
    if (t < 256) { pl[1024 + t] = pv2; al[1024 + t] = av2; }
    __syncthreads();

    const float* W_h  = sp + 0;
    const float* b_h  = sp + 4;
    const float* W_p  = sp + 6;
    const float* b_p  = sp + 16;
    const float* W_a  = sp + 18;
    const float* b_a  = sp + 28;
    const float* ln_w = sp + 30;
    const float* ln_b = sp + 36;
    const float* W_fc = sp + 42;
    const float* b_fc = sp + 78;

    float obuf[12];
    const float hx[2] = { hq.x, hq.z };
    const float hy[2] = { hq.y, hq.w };

    #pragma unroll
    for (int r = 0; r < 2; ++r) {
        const int lr = 2 * t + r;   // local row

        float f[3][2];
        f[0][0] = frelu(W_h[0]*hx[r] + W_h[1]*hy[r] + b_h[0]);
        f[0][1] = frelu(W_h[2]*hx[r] + W_h[3]*hy[r] + b_h[1]);
        {
            float s0 = b_p[0], s1 = b_p[1];
            #pragma unroll
            for (int j = 0; j < 5; ++j) {
                float x = pap[5*lr + j];
                s0 += W_p[j]     * x;
                s1 += W_p[5 + j] * x;
            }
            f[1][0] = frelu(s0); f[1][1] = frelu(s1);
        }
        {
            float s0 = b_a[0], s1 = b_a[1];
            #pragma unroll
            for (int j = 0; j < 5; ++j) {
                float x = aut[5*lr + j];
                s0 += W_a[j]     * x;
                s1 += W_a[5 + j] * x;
            }
            f[2][0] = frelu(s0); f[2][1] = frelu(s1);
        }

        // logits[s][u] = <f_s,f_u>/sqrt(2); softmax over s (axis=1)
        const float inv_sqrt2 = 0.70710678118654752440f;
        float l[3][3];
        #pragma unroll
        for (int s = 0; s < 3; ++s)
            #pragma unroll
            for (int u = 0; u < 3; ++u)
                l[s][u] = (f[s][0]*f[u][0] + f[s][1]*f[u][1]) * inv_sqrt2;

        float w[3][3];
        #pragma unroll
        for (int u = 0; u < 3; ++u) {
            float m  = fmaxf(fmaxf(l[0][u], l[1][u]), l[2][u]);
            float e0 = __expf(l[0][u] - m);
            float e1 = __expf(l[1][u] - m);
            float e2 = __expf(l[2][u] - m);
            float inv = fast_rcp(e0 + e1 + e2);
            w[0][u] = e0 * inv; w[1][u] = e1 * inv; w[2][u] = e2 * inv;
        }

        float att[3][2];
        #pragma unroll
        for (int s = 0; s < 3; ++s) {
            att[s][0] = w[s][0]*f[0][0] + w[s][1]*f[1][0] + w[s][2]*f[2][0];
            att[s][1] = w[s][0]*f[0][1] + w[s][1]*f[1][1] + w[s][2]*f[2][1];
        }

        float mu = (att[0][0]+att[0][1]+att[1][0]+att[1][1]+att[2][0]+att[2][1]) * (1.f/6.f);
        float var = 0.f;
        #pragma unroll
        for (int s = 0; s < 3; ++s) {
            float d0 = att[s][0] - mu, d1 = att[s][1] - mu;
            var += d0*d0 + d1*d1;
        }
        var *= (1.f/6.f);
        float inv_std = fast_rsq(var + EPS);

        float flat[6];
        #pragma unroll
        for (int s = 0; s < 3; ++s) {
            flat[2*s]   = (att[s][0] - mu) * inv_std * ln_w[2*s]   + ln_b[2*s];
            flat[2*s+1] = (att[s][1] - mu) * inv_std * ln_w[2*s+1] + ln_b[2*s+1];
        }

        #pragma unroll
        for (int o = 0; o < 6; ++o) {
            float acc = b_fc[o];
            #pragma unroll
            for (int j = 0; j < 6; ++j) acc += flat[j] * W_fc[6*o + j];
            obuf[6*r + o] = frelu(acc);
        }
    }

    fvec4* o4 = reinterpret_cast<fvec4*>(out + (rowbase + 2 * (size_t)t) * 6);
    fvec4 v0 = { obuf[0], obuf[1], obuf[2],  obuf[3]  };
    fvec4 v1 = { obuf[4], obuf[5], obuf[6],  obuf[7]  };
    fvec4 v2 = { obuf[8], obuf[9], obuf[10], obuf[11] };
    __builtin_nontemporal_store(v0, o4 + 0);
    __builtin_nontemporal_store(v1, o4 + 1);
    __builtin_nontemporal_store(v2, o4 + 2);
}

// Scalar tail kernel (unused for B = 4194304, kept for generality).
__global__ void shattn_tail(
    const float* __restrict__ history,
    const float* __restrict__ paper,
    const float* __restrict__ author,
    const float* __restrict__ W_h, const float* __restrict__ b_h,
    const float* __restrict__ W_p, const float* __restrict__ b_p,
    const float* __restrict__ W_a, const float* __restrict__ b_a,
    const float* __restrict__ ln_w, const float* __restrict__ ln_b,
    const float* __restrict__ W_fc, const float* __restrict__ b_fc,
    float* __restrict__ out, int row0, int nrows)
{
    int r = row0 + blockIdx.x * blockDim.x + threadIdx.x;
    if (r >= nrows) return;

    float f[3][2];
    f[0][0] = frelu(W_h[0]*history[2*r] + W_h[1]*history[2*r+1] + b_h[0]);
    f[0][1] = frelu(W_h[2]*history[2*r] + W_h[3]*history[2*r+1] + b_h[1]);
    {
        float s0 = b_p[0], s1 = b_p[1];
        for (int j = 0; j < 5; ++j) { float x = paper[5*(size_t)r + j]; s0 += W_p[j]*x; s1 += W_p[5+j]*x; }
        f[1][0] = frelu(s0); f[1][1] = frelu(s1);
    }
    {
        float s0 = b_a[0], s1 = b_a[1];
        for (int j = 0; j < 5; ++j) { float x = author[5*(size_t)r + j]; s0 += W_a[j]*x; s1 += W_a[5+j]*x; }
        f[2][0] = frelu(s0); f[2][1] = frelu(s1);
    }
    const float inv_sqrt2 = 0.70710678118654752440f;
    float l[3][3];
    for (int s = 0; s < 3; ++s)
        for (int u = 0; u < 3; ++u)
            l[s][u] = (f[s][0]*f[u][0] + f[s][1]*f[u][1]) * inv_sqrt2;
    float w[3][3];
    for (int u = 0; u < 3; ++u) {
        float m = fmaxf(fmaxf(l[0][u], l[1][u]), l[2][u]);
        float e0 = __expf(l[0][u]-m), e1 = __expf(l[1][u]-m), e2 = __expf(l[2][u]-m);
        float inv = 1.f / (e0+e1+e2);
        w[0][u]=e0*inv; w[1][u]=e1*inv; w[2][u]=e2*inv;
    }
    float att[3][2];
    for (int s = 0; s < 3; ++s) {
        att[s][0] = w[s][0]*f[0][0] + w[s][1]*f[1][0] + w[s][2]*f[2][0];
        att[s][1] = w[s][0]*f[0][1] + w[s][1]*f[1][1] + w[s][2]*f[2][1];
    }
    float mu = (att[0][0]+att[0][1]+att[1][0]+att[1][1]+att[2][0]+att[2][1])/6.f;
    float var = 0.f;
    for (int s = 0; s < 3; ++s) {
        float d0 = att[s][0]-mu, d1 = att[s][1]-mu;
        var += d0*d0 + d1*d1;
    }
    var /= 6.f;
    float inv_std = 1.f / sqrtf(var + EPS);
    float flat[6];
    for (int s = 0; s < 3; ++s) {
        flat[2*s]   = (att[s][0]-mu)*inv_std*ln_w[2*s]   + ln_b[2*s];
        flat[2*s+1] = (att[s][1]-mu)*inv_std*ln_w[2*s+1] + ln_b[2*s+1];
    }
    for (int o = 0; o < 6; ++o) {
        float acc = b_fc[o];
        for (int j = 0; j < 6; ++j) acc += flat[j] * W_fc[6*o+j];
        out[6*(size_t)r + o] = frelu(acc);
    }
}

extern "C" void kernel_launch(void* const* d_in, const int* in_sizes, int n_in,
                              void* d_out, int out_size, void* d_ws, size_t ws_size,
                              hipStream_t stream) {
    const float* history = (const float*)d_in[0];
    const float* paper   = (const float*)d_in[1];
    const float* author  = (const float*)d_in[2];
    const float* W_h  = (const float*)d_in[3];
    const float* b_h  = (const float*)d_in[4];
    const float* W_p  = (const float*)d_in[5];
    const float* b_p  = (const float*)d_in[6];
    const float* W_a  = (const float*)d_in[7];
    const float* b_a  = (const float*)d_in[8];
    const float* ln_w = (const float*)d_in[9];
    const float* ln_b = (const float*)d_in[10];
    const float* W_fc = (const float*)d_in[11];
    const float* b_fc = (const float*)d_in[12];
    float* out = (float*)d_out;

    const int nrows = in_sizes[0] / 2;       // history is [B,2]
    const int full_blocks = nrows / 1024;    // 1024 rows per block

    if (full_blocks > 0)
        shattn_main<<<full_blocks, 512, 0, stream>>>(
            history, paper, author,
            W_h, b_h, W_p, b_p, W_a, b_a, ln_w, ln_b, W_fc, b_fc, out);

    const int done = full_blocks * 1024;
    const int rem  = nrows - done;
    if (rem > 0) {
        int tb = (rem + 255) / 256;
        shattn_tail<<<tb, 256, 0, stream>>>(
            history, paper, author,
            W_h, b_h, W_p, b_p, W_a, b_a, ln_w, ln_b, W_fc, b_fc,
            out, done, nrows);
    }
}

// Round 5
// 55.042 us; speedup vs baseline: 1.1549x; 1.1549x over previous
//
#include <hip/hip_runtime.h>

#define EPS 1e-5f

__device__ __forceinline__ float frelu(float x) { return x > 0.f ? x : 0.f; }
__device__ __forceinline__ float fast_rcp(float x) { return __builtin_amdgcn_rcpf(x); }
__device__ __forceinline__ float fast_rsq(float x) { return __builtin_amdgcn_rsqf(x); }

#define GLB const __attribute__((address_space(1))) void*
#define LDS __attribute__((address_space(3))) void*

// Block = 256 threads, 1 row/thread (256 rows/block; B = 16384 * 256 exactly).
//  - paper/author staged global->LDS via global_load_lds width=16 (no VGPR
//    round-trip, no ds_write): 320 float4 per array per block, linear lane
//    order so the wave-uniform-base semantics match exactly.
//  - per-thread LDS reads lds[5t+j]: bank (5t+j)%32, gcd(5,32)=1 -> 2
//    lanes/bank = conflict-free (m136).
//  - history: float2/lane direct (coalesced); out: 3x float2/lane (24 B/row).
//  - 10.6 KB LDS, small VGPR -> 8 blocks/CU, occupancy cap 100%.
__global__ __launch_bounds__(256) void shattn_main(
    const float* __restrict__ history,
    const float* __restrict__ paper,
    const float* __restrict__ author,
    const float* __restrict__ g_W_h, const float* __restrict__ g_b_h,
    const float* __restrict__ g_W_p, const float* __restrict__ g_b_p,
    const float* __restrict__ g_W_a, const float* __restrict__ g_b_a,
    const float* __restrict__ g_ln_w, const float* __restrict__ g_ln_b,
    const float* __restrict__ g_W_fc, const float* __restrict__ g_b_fc,
    float* __restrict__ out)
{
    __shared__ float sp[84];
    __shared__ float pap[1280];   // 256 rows x 5 f32 = 5 KB
    __shared__ float aut[1280];   // 5 KB

    const int t = threadIdx.x;
    const size_t rowbase = (size_t)blockIdx.x * 256;

    // ---- async global->LDS staging of paper/author (issue first) ----
    const float4* p4 = reinterpret_cast<const float4*>(paper  + rowbase * 5);
    const float4* a4 = reinterpret_cast<const float4*>(author + rowbase * 5);
    float4* pl = reinterpret_cast<float4*>(pap);
    float4* al = reinterpret_cast<float4*>(aut);

    __builtin_amdgcn_global_load_lds((GLB)(p4 + t), (LDS)(pl + t), 16, 0, 0);
    __builtin_amdgcn_global_load_lds((GLB)(a4 + t), (LDS)(al + t), 16, 0, 0);
    if (t < 64) {  // wave 0, fully active: last 64 float4 of each array
        __builtin_amdgcn_global_load_lds((GLB)(p4 + 256 + t), (LDS)(pl + 256 + t), 16, 0, 0);
        __builtin_amdgcn_global_load_lds((GLB)(a4 + 256 + t), (LDS)(al + 256 + t), 16, 0, 0);
    }

    // ---- history row (direct, coalesced float2/lane) ----
    const float2 hrow = reinterpret_cast<const float2*>(history)[rowbase + t];

    // ---- parameters ----
    if (t < 84) {
        float v;
        if      (t < 4)  v = g_W_h[t];
        else if (t < 6)  v = g_b_h[t - 4];
        else if (t < 16) v = g_W_p[t - 6];
        else if (t < 18) v = g_b_p[t - 16];
        else if (t < 28) v = g_W_a[t - 18];
        else if (t < 30) v = g_b_a[t - 28];
        else if (t < 36) v = g_ln_w[t - 30];
        else if (t < 42) v = g_ln_b[t - 36];
        else if (t < 78) v = g_W_fc[t - 42];
        else             v = g_b_fc[t - 78];
        sp[t] = v;
    }
    __syncthreads();

    const float* W_h  = sp + 0;
    const float* b_h  = sp + 4;
    const float* W_p  = sp + 6;
    const float* b_p  = sp + 16;
    const float* W_a  = sp + 18;
    const float* b_a  = sp + 28;
    const float* ln_w = sp + 30;
    const float* ln_b = sp + 36;
    const float* W_fc = sp + 42;
    const float* b_fc = sp + 78;

    // ---- per-row compute ----
    float f[3][2];
    f[0][0] = frelu(W_h[0]*hrow.x + W_h[1]*hrow.y + b_h[0]);
    f[0][1] = frelu(W_h[2]*hrow.x + W_h[3]*hrow.y + b_h[1]);
    {
        float s0 = b_p[0], s1 = b_p[1];
        #pragma unroll
        for (int j = 0; j < 5; ++j) {
            float x = pap[5*t + j];
            s0 += W_p[j]     * x;
            s1 += W_p[5 + j] * x;
        }
        f[1][0] = frelu(s0); f[1][1] = frelu(s1);
    }
    {
        float s0 = b_a[0], s1 = b_a[1];
        #pragma unroll
        for (int j = 0; j < 5; ++j) {
            float x = aut[5*t + j];
            s0 += W_a[j]     * x;
            s1 += W_a[5 + j] * x;
        }
        f[2][0] = frelu(s0); f[2][1] = frelu(s1);
    }

    // logits[s][u] = <f_s,f_u>/sqrt(2); softmax over s (axis=1)
    const float inv_sqrt2 = 0.70710678118654752440f;
    float l[3][3];
    #pragma unroll
    for (int s = 0; s < 3; ++s)
        #pragma unroll
        for (int u = 0; u < 3; ++u)
            l[s][u] = (f[s][0]*f[u][0] + f[s][1]*f[u][1]) * inv_sqrt2;

    float w[3][3];
    #pragma unroll
    for (int u = 0; u < 3; ++u) {
        float m  = fmaxf(fmaxf(l[0][u], l[1][u]), l[2][u]);
        float e0 = __expf(l[0][u] - m);
        float e1 = __expf(l[1][u] - m);
        float e2 = __expf(l[2][u] - m);
        float inv = fast_rcp(e0 + e1 + e2);
        w[0][u] = e0 * inv; w[1][u] = e1 * inv; w[2][u] = e2 * inv;
    }

    float att[3][2];
    #pragma unroll
    for (int s = 0; s < 3; ++s) {
        att[s][0] = w[s][0]*f[0][0] + w[s][1]*f[1][0] + w[s][2]*f[2][0];
        att[s][1] = w[s][0]*f[0][1] + w[s][1]*f[1][1] + w[s][2]*f[2][1];
    }

    float mu = (att[0][0]+att[0][1]+att[1][0]+att[1][1]+att[2][0]+att[2][1]) * (1.f/6.f);
    float var = 0.f;
    #pragma unroll
    for (int s = 0; s < 3; ++s) {
        float d0 = att[s][0] - mu, d1 = att[s][1] - mu;
        var += d0*d0 + d1*d1;
    }
    var *= (1.f/6.f);
    float inv_std = fast_rsq(var + EPS);

    float flat[6];
    #pragma unroll
    for (int s = 0; s < 3; ++s) {
        flat[2*s]   = (att[s][0] - mu) * inv_std * ln_w[2*s]   + ln_b[2*s];
        flat[2*s+1] = (att[s][1] - mu) * inv_std * ln_w[2*s+1] + ln_b[2*s+1];
    }

    float obuf[6];
    #pragma unroll
    for (int o = 0; o < 6; ++o) {
        float acc = b_fc[o];
        #pragma unroll
        for (int j = 0; j < 6; ++j) acc += flat[j] * W_fc[6*o + j];
        obuf[o] = frelu(acc);
    }

    float2* o2 = reinterpret_cast<float2*>(out + (rowbase + (size_t)t) * 6);
    o2[0] = make_float2(obuf[0], obuf[1]);
    o2[1] = make_float2(obuf[2], obuf[3]);
    o2[2] = make_float2(obuf[4], obuf[5]);
}

// Scalar tail kernel (unused for B = 4194304, kept for generality).
__global__ void shattn_tail(
    const float* __restrict__ history,
    const float* __restrict__ paper,
    const float* __restrict__ author,
    const float* __restrict__ W_h, const float* __restrict__ b_h,
    const float* __restrict__ W_p, const float* __restrict__ b_p,
    const float* __restrict__ W_a, const float* __restrict__ b_a,
    const float* __restrict__ ln_w, const float* __restrict__ ln_b,
    const float* __restrict__ W_fc, const float* __restrict__ b_fc,
    float* __restrict__ out, int row0, int nrows)
{
    int r = row0 + blockIdx.x * blockDim.x + threadIdx.x;
    if (r >= nrows) return;

    float f[3][2];
    f[0][0] = frelu(W_h[0]*history[2*r] + W_h[1]*history[2*r+1] + b_h[0]);
    f[0][1] = frelu(W_h[2]*history[2*r] + W_h[3]*history[2*r+1] + b_h[1]);
    {
        float s0 = b_p[0], s1 = b_p[1];
        for (int j = 0; j < 5; ++j) { float x = paper[5*(size_t)r + j]; s0 += W_p[j]*x; s1 += W_p[5+j]*x; }
        f[1][0] = frelu(s0); f[1][1] = frelu(s1);
    }
    {
        float s0 = b_a[0], s1 = b_a[1];
        for (int j = 0; j < 5; ++j) { float x = author[5*(size_t)r + j]; s0 += W_a[j]*x; s1 += W_a[5+j]*x; }
        f[2][0] = frelu(s0); f[2][1] = frelu(s1);
    }
    const float inv_sqrt2 = 0.70710678118654752440f;
    float l[3][3];
    for (int s = 0; s < 3; ++s)
        for (int u = 0; u < 3; ++u)
            l[s][u] = (f[s][0]*f[u][0] + f[s][1]*f[u][1]) * inv_sqrt2;
    float w[3][3];
    for (int u = 0; u < 3; ++u) {
        float m = fmaxf(fmaxf(l[0][u], l[1][u]), l[2][u]);
        float e0 = __expf(l[0][u]-m), e1 = __expf(l[1][u]-m), e2 = __expf(l[2][u]-m);
        float inv = 1.f / (e0+e1+e2);
        w[0][u]=e0*inv; w[1][u]=e1*inv; w[2][u]=e2*inv;
    }
    float att[3][2];
    for (int s = 0; s < 3; ++s) {
        att[s][0] = w[s][0]*f[0][0] + w[s][1]*f[1][0] + w[s][2]*f[2][0];
        att[s][1] = w[s][0]*f[0][1] + w[s][1]*f[1][1] + w[s][2]*f[2][1];
    }
    float mu = (att[0][0]+att[0][1]+att[1][0]+att[1][1]+att[2][0]+att[2][1])/6.f;
    float var = 0.f;
    for (int s = 0; s < 3; ++s) {
        float d0 = att[s][0]-mu, d1 = att[s][1]-mu;
        var += d0*d0 + d1*d1;
    }
    var /= 6.f;
    float inv_std = 1.f / sqrtf(var + EPS);
    float flat[6];
    for (int s = 0; s < 3; ++s) {
        flat[2*s]   = (att[s][0]-mu)*inv_std*ln_w[2*s]   + ln_b[2*s];
        flat[2*s+1] = (att[s][1]-mu)*inv_std*ln_w[2*s+1] + ln_b[2*s+1];
    }
    for (int o = 0; o < 6; ++o) {
        float acc = b_fc[o];
        for (int j = 0; j < 6; ++j) acc += flat[j] * W_fc[6*o+j];
        out[6*(size_t)r + o] = frelu(acc);
    }
}

extern "C" void kernel_launch(void* const* d_in, const int* in_sizes, int n_in,
                              void* d_out, int out_size, void* d_ws, size_t ws_size,
                              hipStream_t stream) {
    const float* history = (const float*)d_in[0];
    const float* paper   = (const float*)d_in[1];
    const float* author  = (const float*)d_in[2];
    const float* W_h  = (const float*)d_in[3];
    const float* b_h  = (const float*)d_in[4];
    const float* W_p  = (const float*)d_in[5];
    const float* b_p  = (const float*)d_in[6];
    const float* W_a  = (const float*)d_in[7];
    const float* b_a  = (const float*)d_in[8];
    const float* ln_w = (const float*)d_in[9];
    const float* ln_b = (const float*)d_in[10];
    const float* W_fc = (const float*)d_in[11];
    const float* b_fc = (const float*)d_in[12];
    float* out = (float*)d_out;

    const int nrows = in_sizes[0] / 2;      // history is [B,2]
    const int full_blocks = nrows / 256;    // 256 rows per block

    if (full_blocks > 0)
        shattn_main<<<full_blocks, 256, 0, stream>>>(
            history, paper, author,
            W_h, b_h, W_p, b_p, W_a, b_a, ln_w, ln_b, W_fc, b_fc, out);

    const int done = full_blocks * 256;
    const int rem  = nrows - done;
    if (rem > 0) {
        int tb = (rem + 255) / 256;
        shattn_tail<<<tb, 256, 0, stream>>>(
            history, paper, author,
            W_h, b_h, W_p, b_p, W_a, b_a, ln_w, ln_b, W_fc, b_fc,
            out, done, nrows);
    }
}

// Round 6
// 54.200 us; speedup vs baseline: 1.1728x; 1.0155x over previous
//
#include <hip/hip_runtime.h>

#define EPS 1e-5f

__device__ __forceinline__ float frelu(float x) { return x > 0.f ? x : 0.f; }
__device__ __forceinline__ float fast_rcp(float x) { return __builtin_amdgcn_rcpf(x); }
__device__ __forceinline__ float fast_rsq(float x) { return __builtin_amdgcn_rsqf(x); }

#define GLB const __attribute__((address_space(1))) void*
#define LDS __attribute__((address_space(3))) void*

// Block = 256 threads, 2 rows/thread: rows t and t+256 (512 rows/block;
// B = 8192 * 512 exactly). Split-row pairing (not adjacent) keeps the
// LDS read pattern lds[5*lr+j] conflict-free: 5*(t+256)+j == 5t+j (mod 32),
// gcd(5,32)=1 -> 2 lanes/bank (free, m136). Adjacent pairing (stride 10)
// would be a 4-way conflict.
//  - paper/author staged global->LDS via global_load_lds width=16:
//    640 float4 per array (256+256+128 lanes), linear lane order.
//  - The ~84 uniform param scalars (read from LDS) are loaded once per
//    thread and serve BOTH rows -> halves per-row param-read overhead.
//  - history: 2x float2/lane direct; out: 6x float2/lane, plain stores.
//  - LDS 20.9 KB -> 7 blocks/CU (28 waves/CU cap).
__global__ __launch_bounds__(256) void shattn_main(
    const float* __restrict__ history,
    const float* __restrict__ paper,
    const float* __restrict__ author,
    const float* __restrict__ g_W_h, const float* __restrict__ g_b_h,
    const float* __restrict__ g_W_p, const float* __restrict__ g_b_p,
    const float* __restrict__ g_W_a, const float* __restrict__ g_b_a,
    const float* __restrict__ g_ln_w, const float* __restrict__ g_ln_b,
    const float* __restrict__ g_W_fc, const float* __restrict__ g_b_fc,
    float* __restrict__ out)
{
    __shared__ float sp[84];
    __shared__ float pap[2560];   // 512 rows x 5 f32 = 10 KB
    __shared__ float aut[2560];   // 10 KB

    const int t = threadIdx.x;
    const size_t rowbase = (size_t)blockIdx.x * 512;

    // ---- async global->LDS staging of paper/author (issue first) ----
    const float4* p4 = reinterpret_cast<const float4*>(paper  + rowbase * 5);
    const float4* a4 = reinterpret_cast<const float4*>(author + rowbase * 5);
    float4* pl = reinterpret_cast<float4*>(pap);
    float4* al = reinterpret_cast<float4*>(aut);

    __builtin_amdgcn_global_load_lds((GLB)(p4 + t),       (LDS)(pl + t),       16, 0, 0);
    __builtin_amdgcn_global_load_lds((GLB)(a4 + t),       (LDS)(al + t),       16, 0, 0);
    __builtin_amdgcn_global_load_lds((GLB)(p4 + 256 + t), (LDS)(pl + 256 + t), 16, 0, 0);
    __builtin_amdgcn_global_load_lds((GLB)(a4 + 256 + t), (LDS)(al + 256 + t), 16, 0, 0);
    if (t < 128) {  // waves 0-1 fully active: last 128 float4 of each array
        __builtin_amdgcn_global_load_lds((GLB)(p4 + 512 + t), (LDS)(pl + 512 + t), 16, 0, 0);
        __builtin_amdgcn_global_load_lds((GLB)(a4 + 512 + t), (LDS)(al + 512 + t), 16, 0, 0);
    }

    // ---- history rows (direct, coalesced float2/lane) ----
    const float2* h2 = reinterpret_cast<const float2*>(history);
    const float2 h0 = h2[rowbase + t];
    const float2 h1 = h2[rowbase + 256 + t];

    // ---- parameters ----
    if (t < 84) {
        float v;
        if      (t < 4)  v = g_W_h[t];
        else if (t < 6)  v = g_b_h[t - 4];
        else if (t < 16) v = g_W_p[t - 6];
        else if (t < 18) v = g_b_p[t - 16];
        else if (t < 28) v = g_W_a[t - 18];
        else if (t < 30) v = g_b_a[t - 28];
        else if (t < 36) v = g_ln_w[t - 30];
        else if (t < 42) v = g_ln_b[t - 36];
        else if (t < 78) v = g_W_fc[t - 42];
        else             v = g_b_fc[t - 78];
        sp[t] = v;
    }
    __syncthreads();

    const float* W_h  = sp + 0;
    const float* b_h  = sp + 4;
    const float* W_p  = sp + 6;
    const float* b_p  = sp + 16;
    const float* W_a  = sp + 18;
    const float* b_a  = sp + 28;
    const float* ln_w = sp + 30;
    const float* ln_b = sp + 36;
    const float* W_fc = sp + 42;
    const float* b_fc = sp + 78;

    float obuf[12];

    #pragma unroll
    for (int r = 0; r < 2; ++r) {
        const int   lr   = t + 256 * r;               // local row (conflict-free pattern)
        const float hx   = (r == 0) ? h0.x : h1.x;
        const float hy   = (r == 0) ? h0.y : h1.y;

        float f[3][2];
        f[0][0] = frelu(W_h[0]*hx + W_h[1]*hy + b_h[0]);
        f[0][1] = frelu(W_h[2]*hx + W_h[3]*hy + b_h[1]);
        {
            float s0 = b_p[0], s1 = b_p[1];
            #pragma unroll
            for (int j = 0; j < 5; ++j) {
                float x = pap[5*lr + j];
                s0 += W_p[j]     * x;
                s1 += W_p[5 + j] * x;
            }
            f[1][0] = frelu(s0); f[1][1] = frelu(s1);
        }
        {
            float s0 = b_a[0], s1 = b_a[1];
            #pragma unroll
            for (int j = 0; j < 5; ++j) {
                float x = aut[5*lr + j];
                s0 += W_a[j]     * x;
                s1 += W_a[5 + j] * x;
            }
            f[2][0] = frelu(s0); f[2][1] = frelu(s1);
        }

        // logits[s][u] = <f_s,f_u>/sqrt(2); softmax over s (axis=1)
        const float inv_sqrt2 = 0.70710678118654752440f;
        float l[3][3];
        #pragma unroll
        for (int s = 0; s < 3; ++s)
            #pragma unroll
            for (int u = 0; u < 3; ++u)
                l[s][u] = (f[s][0]*f[u][0] + f[s][1]*f[u][1]) * inv_sqrt2;

        float w[3][3];
        #pragma unroll
        for (int u = 0; u < 3; ++u) {
            float m  = fmaxf(fmaxf(l[0][u], l[1][u]), l[2][u]);
            float e0 = __expf(l[0][u] - m);
            float e1 = __expf(l[1][u] - m);
            float e2 = __expf(l[2][u] - m);
            float inv = fast_rcp(e0 + e1 + e2);
            w[0][u] = e0 * inv; w[1][u] = e1 * inv; w[2][u] = e2 * inv;
        }

        float att[3][2];
        #pragma unroll
        for (int s = 0; s < 3; ++s) {
            att[s][0] = w[s][0]*f[0][0] + w[s][1]*f[1][0] + w[s][2]*f[2][0];
            att[s][1] = w[s][0]*f[0][1] + w[s][1]*f[1][1] + w[s][2]*f[2][1];
        }

        float mu = (att[0][0]+att[0][1]+att[1][0]+att[1][1]+att[2][0]+att[2][1]) * (1.f/6.f);
        float var = 0.f;
        #pragma unroll
        for (int s = 0; s < 3; ++s) {
            float d0 = att[s][0] - mu, d1 = att[s][1] - mu;
            var += d0*d0 + d1*d1;
        }
        var *= (1.f/6.f);
        float inv_std = fast_rsq(var + EPS);

        float flat[6];
        #pragma unroll
        for (int s = 0; s < 3; ++s) {
            flat[2*s]   = (att[s][0] - mu) * inv_std * ln_w[2*s]   + ln_b[2*s];
            flat[2*s+1] = (att[s][1] - mu) * inv_std * ln_w[2*s+1] + ln_b[2*s+1];
        }

        #pragma unroll
        for (int o = 0; o < 6; ++o) {
            float acc = b_fc[o];
            #pragma unroll
            for (int j = 0; j < 6; ++j) acc += flat[j] * W_fc[6*o + j];
            obuf[6*r + o] = frelu(acc);
        }
    }

    // stores: row t and row t+256, 3x float2 each (coalesced across lanes)
    float2* o2a = reinterpret_cast<float2*>(out + (rowbase + (size_t)t) * 6);
    o2a[0] = make_float2(obuf[0], obuf[1]);
    o2a[1] = make_float2(obuf[2], obuf[3]);
    o2a[2] = make_float2(obuf[4], obuf[5]);
    float2* o2b = reinterpret_cast<float2*>(out + (rowbase + 256 + (size_t)t) * 6);
    o2b[0] = make_float2(obuf[6],  obuf[7]);
    o2b[1] = make_float2(obuf[8],  obuf[9]);
    o2b[2] = make_float2(obuf[10], obuf[11]);
}

// Scalar tail kernel (unused for B = 4194304, kept for generality).
__global__ void shattn_tail(
    const float* __restrict__ history,
    const float* __restrict__ paper,
    const float* __restrict__ author,
    const float* __restrict__ W_h, const float* __restrict__ b_h,
    const float* __restrict__ W_p, const float* __restrict__ b_p,
    const float* __restrict__ W_a, const float* __restrict__ b_a,
    const float* __restrict__ ln_w, const float* __restrict__ ln_b,
    const float* __restrict__ W_fc, const float* __restrict__ b_fc,
    float* __restrict__ out, int row0, int nrows)
{
    int r = row0 + blockIdx.x * blockDim.x + threadIdx.x;
    if (r >= nrows) return;

    float f[3][2];
    f[0][0] = frelu(W_h[0]*history[2*r] + W_h[1]*history[2*r+1] + b_h[0]);
    f[0][1] = frelu(W_h[2]*history[2*r] + W_h[3]*history[2*r+1] + b_h[1]);
    {
        float s0 = b_p[0], s1 = b_p[1];
        for (int j = 0; j < 5; ++j) { float x = paper[5*(size_t)r + j]; s0 += W_p[j]*x; s1 += W_p[5+j]*x; }
        f[1][0] = frelu(s0); f[1][1] = frelu(s1);
    }
    {
        float s0 = b_a[0], s1 = b_a[1];
        for (int j = 0; j < 5; ++j) { float x = author[5*(size_t)r + j]; s0 += W_a[j]*x; s1 += W_a[5+j]*x; }
        f[2][0] = frelu(s0); f[2][1] = frelu(s1);
    }
    const float inv_sqrt2 = 0.70710678118654752440f;
    float l[3][3];
    for (int s = 0; s < 3; ++s)
        for (int u = 0; u < 3; ++u)
            l[s][u] = (f[s][0]*f[u][0] + f[s][1]*f[u][1]) * inv_sqrt2;
    float w[3][3];
    for (int u = 0; u < 3; ++u) {
        float m = fmaxf(fmaxf(l[0][u], l[1][u]), l[2][u]);
        float e0 = __expf(l[0][u]-m), e1 = __expf(l[1][u]-m), e2 = __expf(l[2][u]-m);
        float inv = 1.f / (e0+e1+e2);
        w[0][u]=e0*inv; w[1][u]=e1*inv; w[2][u]=e2*inv;
    }
    float att[3][2];
    for (int s = 0; s < 3; ++s) {
        att[s][0] = w[s][0]*f[0][0] + w[s][1]*f[1][0] + w[s][2]*f[2][0];
        att[s][1] = w[s][0]*f[0][1] + w[s][1]*f[1][1] + w[s][2]*f[2][1];
    }
    float mu = (att[0][0]+att[0][1]+att[1][0]+att[1][1]+att[2][0]+att[2][1])/6.f;
    float var = 0.f;
    for (int s = 0; s < 3; ++s) {
        float d0 = att[s][0]-mu, d1 = att[s][1]-mu;
        var += d0*d0 + d1*d1;
    }
    var /= 6.f;
    float inv_std = 1.f / sqrtf(var + EPS);
    float flat[6];
    for (int s = 0; s < 3; ++s) {
        flat[2*s]   = (att[s][0]-mu)*inv_std*ln_w[2*s]   + ln_b[2*s];
        flat[2*s+1] = (att[s][1]-mu)*inv_std*ln_w[2*s+1] + ln_b[2*s+1];
    }
    for (int o = 0; o < 6; ++o) {
        float acc = b_fc[o];
        for (int j = 0; j < 6; ++j) acc += flat[j] * W_fc[6*o+j];
        out[6*(size_t)r + o] = frelu(acc);
    }
}

extern "C" void kernel_launch(void* const* d_in, const int* in_sizes, int n_in,
                              void* d_out, int out_size, void* d_ws, size_t ws_size,
                              hipStream_t stream) {
    const float* history = (const float*)d_in[0];
    const float* paper   = (const float*)d_in[1];
    const float* author  = (const float*)d_in[2];
    const float* W_h  = (const float*)d_in[3];
    const float* b_h  = (const float*)d_in[4];
    const float* W_p  = (const float*)d_in[5];
    const float* b_p  = (const float*)d_in[6];
    const float* W_a  = (const float*)d_in[7];
    const float* b_a  = (const float*)d_in[8];
    const float* ln_w = (const float*)d_in[9];
    const float* ln_b = (const float*)d_in[10];
    const float* W_fc = (const float*)d_in[11];
    const float* b_fc = (const float*)d_in[12];
    float* out = (float*)d_out;

    const int nrows = in_sizes[0] / 2;      // history is [B,2]
    const int full_blocks = nrows / 512;    // 512 rows per block

    if (full_blocks > 0)
        shattn_main<<<full_blocks, 256, 0, stream>>>(
            history, paper, author,
            W_h, b_h, W_p, b_p, W_a, b_a, ln_w, ln_b, W_fc, b_fc, out);

    const int done = full_blocks * 512;
    const int rem  = nrows - done;
    if (rem > 0) {
        int tb = (rem + 255) / 256;
        shattn_tail<<<tb, 256, 0, stream>>>(
            history, paper, author,
            W_h, b_h, W_p, b_p, W_a, b_a, ln_w, ln_b, W_fc, b_fc,
            out, done, nrows);
    }
}